// Round 9
// baseline (464.094 us; speedup 1.0000x reference)
//
#include <hip/hip_runtime.h>
#include <hip/hip_fp16.h>

// GCN on MI355X — bucket-sort CSR build + fp16 shfl-gather + MFMA GEMM.
//
// Algebra: layer2 collapses through the linear head:
//   out = segsum((relu(c1) . (W2@Wl) * ns)[src], dst)*nd + (b2@Wl + bl)
// so only a per-node SCALAR feeds the second aggregation.
//
// R8 change: CSR build was read-bound on range-filtered re-reads (hist 4x,
// fill 8x). Now: k_hist also emits per-(range,chunk) totals; k_bucket reads
// edges ONCE and ballot-rank-appends (src,dst) into per-(range,chunk) segments;
// k_fill2 reads only its segment (no filter) and writes csr in the XCD-aligned
// window. agg_rdot reverts to the proven shfl form (uniform loads were slower),
// unrolled to 16 edges / 8 gathers in flight.

#define WAVE 64
#define NRANGE 8
#define NPAIR 4

typedef _Float16 f16x8 __attribute__((ext_vector_type(8)));
typedef float f32x4 __attribute__((ext_vector_type(4)));

// ---- packed histogram + per-(range,chunk) totals (dst slice only) ----
__global__ __launch_bounds__(256) void k_hist(const int* __restrict__ srcArr,
                                              const int* __restrict__ dstArr,
                                              unsigned* __restrict__ partial_s,
                                              unsigned* __restrict__ partial_d,
                                              unsigned* __restrict__ cnt,
                                              int E, int B, int C, int chunkE) {
    extern __shared__ unsigned hist[];
    __shared__ unsigned red[8];
    const int pr = blockIdx.x & (NPAIR - 1);
    const int c = blockIdx.x >> 2;
    const int lo = pr * 2 * B;
    const int* nodes = blockIdx.y ? dstArr : srcArr;
    unsigned* partial = blockIdx.y ? partial_d : partial_s;

    for (int b = threadIdx.x; b < B; b += 256) hist[b] = 0u;
    __syncthreads();

    const int beg = c * chunkE, end = min(beg + chunkE, E);
    const int n4 = (end - beg) >> 2;           // beg 4-aligned (chunkE %4==0)
    const int4* p = (const int4*)(nodes + beg);
    for (int j = threadIdx.x; j < n4; j += 256) {
        int4 v = p[j];
        int a;
        a = v.x - lo; if ((unsigned)a < (unsigned)(2 * B)) { int h = a >= B; atomicAdd(&hist[a - (h ? B : 0)], h ? 0x10000u : 1u); }
        a = v.y - lo; if ((unsigned)a < (unsigned)(2 * B)) { int h = a >= B; atomicAdd(&hist[a - (h ? B : 0)], h ? 0x10000u : 1u); }
        a = v.z - lo; if ((unsigned)a < (unsigned)(2 * B)) { int h = a >= B; atomicAdd(&hist[a - (h ? B : 0)], h ? 0x10000u : 1u); }
        a = v.w - lo; if ((unsigned)a < (unsigned)(2 * B)) { int h = a >= B; atomicAdd(&hist[a - (h ? B : 0)], h ? 0x10000u : 1u); }
    }
    for (int j = beg + (n4 << 2) + threadIdx.x; j < end; j += 256) {
        int a = nodes[j] - lo;
        if ((unsigned)a < (unsigned)(2 * B)) { int h = a >= B; atomicAdd(&hist[a - (h ? B : 0)], h ? 0x10000u : 1u); }
    }
    __syncthreads();
    unsigned* outp = partial + (size_t)(pr * C + c) * B;
    unsigned slo = 0, shi = 0;
    for (int b = threadIdx.x; b < B; b += 256) {
        unsigned h = hist[b];
        outp[b] = h;
        slo += h & 0xffffu;
        shi += h >> 16;
    }
    if (blockIdx.y == 1) {                       // dst slice: emit segment totals
#pragma unroll
        for (int off = 32; off; off >>= 1) {
            slo += __shfl_xor((int)slo, off);
            shi += __shfl_xor((int)shi, off);
        }
        if ((threadIdx.x & 63) == 0) {
            red[(threadIdx.x >> 6) * 2] = slo;
            red[(threadIdx.x >> 6) * 2 + 1] = shi;
        }
        __syncthreads();
        if (threadIdx.x == 0) {
            cnt[(2 * pr) * C + c]     = red[0] + red[2] + red[4] + red[6];
            cnt[(2 * pr + 1) * C + c] = red[1] + red[3] + red[5] + red[7];
        }
    }
}

// ---- per bin-pair: sum packed partials -> norms/deg; packed exclusive prefix ----
__global__ __launch_bounds__(256) void k_reduce_norm(const unsigned* __restrict__ partial_s,
                                                     unsigned* __restrict__ partial_d,
                                                     float* __restrict__ norm_s,
                                                     float* __restrict__ norm_d,
                                                     unsigned* __restrict__ deg_d,
                                                     int N, int B, int C) {
    int t = blockIdx.x * 256 + threadIdx.x;   // [0, NPAIR*B)
    if (t >= NPAIR * B) return;
    int pr = t / B, b = t - pr * B;
    int n0 = pr * 2 * B + b, n1 = n0 + B;
    size_t base = (size_t)(pr * C) * B + b;
    unsigned ds = 0;
    for (int c = 0; c < C; ++c) ds += partial_s[base + (size_t)c * B];  // packed; halves can't carry
    unsigned run = 0;
    for (int c = 0; c < C; ++c) {
        size_t ix = base + (size_t)c * B;
        unsigned v = partial_d[ix];
        partial_d[ix] = run;                    // packed exclusive prefix
        run += v;
    }
    unsigned ds0 = ds & 0xffffu, ds1 = ds >> 16;
    unsigned dd0 = run & 0xffffu, dd1 = run >> 16;
    if (n0 < N) {
        deg_d[n0] = dd0;
        norm_s[n0] = ds0 ? rsqrtf((float)ds0) : 0.0f;
        norm_d[n0] = dd0 ? rsqrtf((float)dd0) : 0.0f;
    }
    if (n1 < N) {
        deg_d[n1] = dd1;
        norm_s[n1] = ds1 ? rsqrtf((float)ds1) : 0.0f;
        norm_d[n1] = dd1 ? rsqrtf((float)dd1) : 0.0f;
    }
}

// w2l[c] = sum_j W2[c][j]*Wl[j]; c0 = b2.Wl + bl
__global__ void k_w2l(const float* __restrict__ W2, const float* __restrict__ b2,
                      const float* __restrict__ Wl, const float* __restrict__ bl,
                      float* __restrict__ w2l, float* __restrict__ c0) {
    int c = threadIdx.x; // 64 threads
    float acc = 0.f;
#pragma unroll
    for (int j = 0; j < 32; ++j) acc += W2[c * 32 + j] * Wl[j];
    w2l[c] = acc;
    if (c == 0) {
        float s = 0.f;
#pragma unroll
        for (int j = 0; j < 32; ++j) s += b2[j] * Wl[j];
        *c0 = s + bl[0];
    }
}

// ---- W1 [128][64] fp32 -> wt [64][128] fp16 (transposed), once ----
__global__ __launch_bounds__(256) void k_wt(const float* __restrict__ W1,
                                            _Float16* __restrict__ wt) {
    int t = threadIdx.x;
    for (int i = 0; i < 32; ++i) {
        int e = i * 256 + t;       // 8192 elements
        int k = e >> 6, n = e & 63;
        wt[n * 128 + k] = (_Float16)W1[e];
    }
}

// ---- scan: deg_d -> exclusive offsets (N+1) ----
__global__ __launch_bounds__(256) void k_blocksum(const unsigned* __restrict__ deg,
                                                  unsigned* __restrict__ partial, int N) {
    __shared__ unsigned sw[4];
    int i = blockIdx.x * 256 + threadIdx.x;
    unsigned v = (i < N) ? deg[i] : 0u;
#pragma unroll
    for (int off = 32; off; off >>= 1) v += __shfl_xor((int)v, off);
    if ((threadIdx.x & 63) == 0) sw[threadIdx.x >> 6] = v;
    __syncthreads();
    if (threadIdx.x == 0) partial[blockIdx.x] = sw[0] + sw[1] + sw[2] + sw[3];
}

__global__ __launch_bounds__(512) void k_scanpartial(const unsigned* __restrict__ partial,
                                                     unsigned* __restrict__ blockoff,
                                                     unsigned* __restrict__ offsets,
                                                     int nb, int N) {
    __shared__ unsigned s[512];
    int t = threadIdx.x;
    unsigned v = (t < nb) ? partial[t] : 0u;
    s[t] = v;
    __syncthreads();
    for (int off = 1; off < 512; off <<= 1) {
        unsigned a = (t >= off) ? s[t - off] : 0u;
        __syncthreads();
        s[t] += a;
        __syncthreads();
    }
    if (t < nb) blockoff[t] = s[t] - v;       // exclusive
    if (t == nb - 1) offsets[N] = s[t];       // total = E
}

__global__ __launch_bounds__(256) void k_offsets(const unsigned* __restrict__ deg,
                                                 const unsigned* __restrict__ blockoff,
                                                 unsigned* __restrict__ offsets, int N) {
    __shared__ unsigned s[256];
    int t = threadIdx.x;
    int i = blockIdx.x * 256 + t;
    unsigned v = (i < N) ? deg[i] : 0u;
    s[t] = v;
    __syncthreads();
    for (int off = 1; off < 256; off <<= 1) {
        unsigned a = (t >= off) ? s[t - off] : 0u;
        __syncthreads();
        s[t] += a;
        __syncthreads();
    }
    if (i < N) offsets[i] = blockoff[blockIdx.x] + s[t] - v;
}

// ---- scan of cnt[r][c] (nseg = NRANGE*C <= 256) -> segBase ----
__global__ __launch_bounds__(256) void k_scancnt(const unsigned* __restrict__ cnt,
                                                 unsigned* __restrict__ segBase, int nseg) {
    __shared__ unsigned s[256];
    int t = threadIdx.x;
    unsigned v = (t < nseg) ? cnt[t] : 0u;
    s[t] = v;
    __syncthreads();
    for (int off = 1; off < 256; off <<= 1) {
        unsigned a = (t >= off) ? s[t - off] : 0u;
        __syncthreads();
        s[t] += a;
        __syncthreads();
    }
    if (t < nseg) segBase[t] = s[t] - v;      // exclusive
}

// ---- bucketize: read edges ONCE; ballot-ranked append (src,dst) into
//      per-(range,chunk) segments of ebuf. 8 LDS counters, no global atomics. ----
__global__ __launch_bounds__(256) void k_bucket(const int* __restrict__ src,
                                                const int* __restrict__ dst,
                                                const unsigned* __restrict__ segBase,
                                                uint2* __restrict__ ebuf,
                                                int E, int B, int C, int chunkE) {
    __shared__ unsigned lcnt[NRANGE];
    const int c = blockIdx.x;
    const int lane = threadIdx.x & 63;
    if (threadIdx.x < NRANGE) lcnt[threadIdx.x] = 0u;
    __syncthreads();

    unsigned sb[NRANGE];
#pragma unroll
    for (int r = 0; r < NRANGE; ++r) sb[r] = segBase[r * C + c];

    const int beg = c * chunkE, end = min(beg + chunkE, E);
    for (int i = beg + (int)threadIdx.x; i < end; i += 256) {
        int d = dst[i];
        int s = src[i];
        int r4 = (d >= 4 * B) ? 4 : 0;
        int r2 = (d >= (r4 + 2) * B) ? 2 : 0;
        int r = r4 + r2 + ((d >= (r4 + r2 + 1) * B) ? 1 : 0);
#pragma unroll
        for (int rr = 0; rr < NRANGE; ++rr) {
            unsigned long long m = __ballot(r == rr);
            if (m) {
                int leader = __ffsll((long long)m) - 1;
                unsigned base = 0;
                if (lane == leader) base = atomicAdd(&lcnt[rr], (unsigned)__popcll(m));
                base = (unsigned)__shfl((int)base, leader);
                if (r == rr) {
                    unsigned before = (unsigned)__popcll(m & ((1ull << lane) - 1ull));
                    ebuf[sb[rr] + base + before] = make_uint2((unsigned)s, (unsigned)d);
                }
            }
        }
    }
}

// ---- fill2: block (r,c) reads ONLY its segment; LDS cursors hold ABSOLUTE
//      csr positions; r = blockIdx&7 keeps each csr window on one XCD ----
__global__ __launch_bounds__(256) void k_fill2(const uint2* __restrict__ ebuf,
                                               const unsigned* __restrict__ segBase,
                                               const unsigned* __restrict__ cnt,
                                               const unsigned* __restrict__ offsets,
                                               const unsigned* __restrict__ rel,
                                               unsigned* __restrict__ csr,
                                               int N, int B, int C) {
    extern __shared__ unsigned curs[];
    const int r = blockIdx.x & (NRANGE - 1);
    const int c = blockIdx.x >> 3;
    const int lo = r * B;
    const int bins = min(B, N - lo);
    const int pr = r >> 1, hs = (r & 1) << 4;
    const unsigned* relp = rel + (size_t)(pr * C + c) * B;
    for (int b = threadIdx.x; b < bins; b += 256)
        curs[b] = offsets[lo + b] + ((relp[b] >> hs) & 0xffffu);
    __syncthreads();

    const unsigned s0 = segBase[r * C + c];
    const unsigned len = cnt[r * C + c];
    for (unsigned i = s0 + threadIdx.x; i < s0 + len; i += 256) {
        uint2 e = ebuf[i];
        int a = (int)e.y - lo;
        if ((unsigned)a < (unsigned)bins)
            csr[atomicAdd(&curs[a], 1u)] = e.x;
    }
}

// h1h = fp16( (x * ns[:,None]) @ W1 )  via MFMA 16x16x32_f16.
__global__ __launch_bounds__(256) void k_gemm1(const float* __restrict__ x,
                                               const _Float16* __restrict__ wt,
                                               const float* __restrict__ norm_s,
                                               __half* __restrict__ h1h, int N) {
    __shared__ __align__(16) _Float16 xs[64 * 128];
    const int tid = threadIdx.x, lane = tid & 63, wv = tid >> 6;
    const int r0 = blockIdx.x * 64;

    // B fragments: col = nt*16 + (lane&15), k = kt*32 + (lane>>4)*8 + b
    f16x8 bf[4][4];
#pragma unroll
    for (int kt = 0; kt < 4; ++kt)
#pragma unroll
        for (int nt = 0; nt < 4; ++nt)
            bf[kt][nt] = *(const f16x8*)&wt[(nt * 16 + (lane & 15)) * 128 +
                                            kt * 32 + (lane >> 4) * 8];

    // stage x tile -> fp16 LDS, swizzled (byte ^= (r&7)<<4)
#pragma unroll
    for (int it = 0; it < 8; ++it) {
        int e = it * 256 + tid;              // float4 index, 2048 total
        int r = e >> 5, c = e & 31;          // row, float4-within-row
        int row = r0 + r;
        float4 v = (row < N) ? ((const float4*)x)[(size_t)row * 32 + c]
                             : make_float4(0.f, 0.f, 0.f, 0.f);
        __half2 lo2 = __floats2half2_rn(v.x, v.y);
        __half2 hi2 = __floats2half2_rn(v.z, v.w);
        uint2 pk;
        pk.x = *(unsigned*)&lo2;
        pk.y = *(unsigned*)&hi2;
        int byte = r * 256 + c * 8;
        byte ^= (r & 7) << 4;
        *(uint2*)((char*)xs + byte) = pk;
    }
    __syncthreads();

    f32x4 acc[4] = {};
    const int rloc = wv * 16 + (lane & 15);   // A row within block tile
#pragma unroll
    for (int kt = 0; kt < 4; ++kt) {
        int byte = rloc * 256 + (kt * 32 + (lane >> 4) * 8) * 2;
        byte ^= (rloc & 7) << 4;
        f16x8 af = *(const f16x8*)((char*)xs + byte);
#pragma unroll
        for (int nt = 0; nt < 4; ++nt)
            acc[nt] = __builtin_amdgcn_mfma_f32_16x16x32_f16(af, bf[kt][nt], acc[nt], 0, 0, 0);
    }

    // D: col = nt*16 + (lane&15), row = wv*16 + (lane>>4)*4 + j
#pragma unroll
    for (int j = 0; j < 4; ++j) {
        int row = r0 + wv * 16 + (lane >> 4) * 4 + j;
        if (row < N) {
            float ns = norm_s[row];
#pragma unroll
            for (int nt = 0; nt < 4; ++nt)
                h1h[(size_t)row * 64 + nt * 16 + (lane & 15)] =
                    __float2half(acc[nt][j] * ns);
        }
    }
}

// One wave per node; coalesced csr load + shfl broadcast; 2 edges per step
// (lanes 0-31 / 32-63), __half2 per lane = 256B/instr; 8 gathers in flight.
__global__ __launch_bounds__(256) void k_agg_rdot(const unsigned* __restrict__ offsets,
                                                  const unsigned* __restrict__ csr,
                                                  const __half* __restrict__ h1h,
                                                  const float* __restrict__ norm_s,
                                                  const float* __restrict__ norm_d,
                                                  const float* __restrict__ b1,
                                                  const float* __restrict__ w2l,
                                                  float* __restrict__ s_node, int N) {
    const int lane = threadIdx.x & 63;
    const int slot = lane >> 5;    // which edge of the pair
    const int p = lane & 31;       // channel pair -> channels 2p, 2p+1
    const int v = (blockIdx.x * 256 + threadIdx.x) >> 6;
    if (v >= N) return;
    const unsigned beg = offsets[v], end = offsets[v + 1];

    float ax = 0.f, ay = 0.f;
    for (unsigned base = beg; base < end; base += WAVE) {
        const int n = (int)min((unsigned)WAVE, end - base);
        int sv = (lane < n) ? (int)csr[base + lane] : 0;
        int i = 0;
        for (; i + 16 <= n; i += 16) {  // 8 independent 256B gathers in flight
            int s0 = __shfl(sv, i + 0 + slot);
            int s1 = __shfl(sv, i + 2 + slot);
            int s2 = __shfl(sv, i + 4 + slot);
            int s3 = __shfl(sv, i + 6 + slot);
            int s4 = __shfl(sv, i + 8 + slot);
            int s5 = __shfl(sv, i + 10 + slot);
            int s6 = __shfl(sv, i + 12 + slot);
            int s7 = __shfl(sv, i + 14 + slot);
            unsigned u0 = *(const unsigned*)&h1h[(size_t)s0 * 64 + 2 * p];
            unsigned u1 = *(const unsigned*)&h1h[(size_t)s1 * 64 + 2 * p];
            unsigned u2 = *(const unsigned*)&h1h[(size_t)s2 * 64 + 2 * p];
            unsigned u3 = *(const unsigned*)&h1h[(size_t)s3 * 64 + 2 * p];
            unsigned u4 = *(const unsigned*)&h1h[(size_t)s4 * 64 + 2 * p];
            unsigned u5 = *(const unsigned*)&h1h[(size_t)s5 * 64 + 2 * p];
            unsigned u6 = *(const unsigned*)&h1h[(size_t)s6 * 64 + 2 * p];
            unsigned u7 = *(const unsigned*)&h1h[(size_t)s7 * 64 + 2 * p];
            float2 f0 = __half22float2(*(__half2*)&u0);
            float2 f1 = __half22float2(*(__half2*)&u1);
            float2 f2 = __half22float2(*(__half2*)&u2);
            float2 f3 = __half22float2(*(__half2*)&u3);
            float2 f4 = __half22float2(*(__half2*)&u4);
            float2 f5 = __half22float2(*(__half2*)&u5);
            float2 f6 = __half22float2(*(__half2*)&u6);
            float2 f7 = __half22float2(*(__half2*)&u7);
            ax += ((f0.x + f1.x) + (f2.x + f3.x)) + ((f4.x + f5.x) + (f6.x + f7.x));
            ay += ((f0.y + f1.y) + (f2.y + f3.y)) + ((f4.y + f5.y) + (f6.y + f7.y));
        }
        for (; i + 8 <= n; i += 8) {
            int s0 = __shfl(sv, i + 0 + slot);
            int s1 = __shfl(sv, i + 2 + slot);
            int s2 = __shfl(sv, i + 4 + slot);
            int s3 = __shfl(sv, i + 6 + slot);
            unsigned u0 = *(const unsigned*)&h1h[(size_t)s0 * 64 + 2 * p];
            unsigned u1 = *(const unsigned*)&h1h[(size_t)s1 * 64 + 2 * p];
            unsigned u2 = *(const unsigned*)&h1h[(size_t)s2 * 64 + 2 * p];
            unsigned u3 = *(const unsigned*)&h1h[(size_t)s3 * 64 + 2 * p];
            float2 f0 = __half22float2(*(__half2*)&u0);
            float2 f1 = __half22float2(*(__half2*)&u1);
            float2 f2 = __half22float2(*(__half2*)&u2);
            float2 f3 = __half22float2(*(__half2*)&u3);
            ax += (f0.x + f1.x) + (f2.x + f3.x);
            ay += (f0.y + f1.y) + (f2.y + f3.y);
        }
        for (; i < n; i += 2) {
            int e = i + slot;
            int s = __shfl(sv, min(e, n - 1));
            if (e < n) {
                unsigned u = *(const unsigned*)&h1h[(size_t)s * 64 + 2 * p];
                float2 f = __half22float2(*(__half2*)&u);
                ax += f.x; ay += f.y;
            }
        }
    }
    // merge the two edge-slots: lanes l and l^32 hold the same channel pair
    ax += __shfl_xor(ax, 32);
    ay += __shfl_xor(ay, 32);

    float nd = norm_d[v];
    float t = fmaxf(fmaf(ax, nd, b1[2 * p]), 0.f) * w2l[2 * p]
            + fmaxf(fmaf(ay, nd, b1[2 * p + 1]), 0.f) * w2l[2 * p + 1];
#pragma unroll
    for (int off = 16; off; off >>= 1) t += __shfl_xor(t, off);
    if (lane == 0) s_node[v] = t * norm_s[v];
}

// out[v] = nd[v] * sum_{in-edges} s_node[src] + c0
__global__ __launch_bounds__(256) void k_out(const unsigned* __restrict__ offsets,
                                             const unsigned* __restrict__ csr,
                                             const float* __restrict__ s_node,
                                             const float* __restrict__ norm_d,
                                             const float* __restrict__ c0,
                                             float* __restrict__ out, int N) {
    int v = blockIdx.x * 256 + threadIdx.x;
    if (v >= N) return;
    unsigned beg = offsets[v], end = offsets[v + 1];
    float sum = 0.f;
    unsigned j = beg;
    for (; j + 4 <= end; j += 4) {
        float a = s_node[csr[j + 0]], b = s_node[csr[j + 1]];
        float c = s_node[csr[j + 2]], d = s_node[csr[j + 3]];
        sum += a + b + c + d;
    }
    for (; j < end; ++j) sum += s_node[csr[j]];
    out[v] = fmaf(sum, norm_d[v], *c0);
}

extern "C" void kernel_launch(void* const* d_in, const int* in_sizes, int n_in,
                              void* d_out, int out_size, void* d_ws, size_t ws_size,
                              hipStream_t stream) {
    const float* x  = (const float*)d_in[0];
    const int*   ei = (const int*)d_in[1];
    const float* W1 = (const float*)d_in[2];
    const float* b1 = (const float*)d_in[3];
    const float* W2 = (const float*)d_in[4];
    const float* b2 = (const float*)d_in[5];
    const float* Wl = (const float*)d_in[6];
    const float* bl = (const float*)d_in[7];

    const int N = in_sizes[0] / 128;
    const int E = in_sizes[1] / 2;
    const int* src = ei;
    const int* dst = ei + E;
    const int NB = (N + 255) / 256;
    const int B = (N + NRANGE - 1) / NRANGE;       // bins per range (12500)

    // pick chunk count C so packed partials + ebuf fit the workspace
    size_t baseBytes = 0;
    {
        auto pad = [](size_t b) { return (b + 255) & ~(size_t)255; };
        baseBytes = pad((size_t)N * 4) * 3 + pad((size_t)(N + 1) * 4) +
                    pad((size_t)NB * 4) * 2 + pad((size_t)N * 64 * 2) +
                    pad((size_t)E * 4) + pad((size_t)N * 4) + pad(64 * 4) + pad(4) +
                    pad(64 * 128 * 2) + pad((size_t)E * 8) + pad(256 * 4) * 2;
    }
    int C = 32;
    while (C > 4 && baseBytes + 2ull * NPAIR * C * B * 4ull > ws_size) C >>= 1;
    const int chunkE = (((E + C - 1) / C) + 3) & ~3;
    const int nseg = NRANGE * C;

    char* w = (char*)d_ws;
    auto alloc = [&](size_t bytes) -> void* {
        void* r = (void*)w;
        w += (bytes + 255) & ~(size_t)255;
        return r;
    };
    float*    norm_s    = (float*)alloc((size_t)N * 4);
    float*    norm_d    = (float*)alloc((size_t)N * 4);
    unsigned* deg_d     = (unsigned*)alloc((size_t)N * 4);
    unsigned* offsets   = (unsigned*)alloc((size_t)(N + 1) * 4);
    unsigned* partial   = (unsigned*)alloc((size_t)NB * 4);
    unsigned* blockoff  = (unsigned*)alloc((size_t)NB * 4);
    __half*   h1h       = (__half*)alloc((size_t)N * 64 * 2);
    unsigned* csr       = (unsigned*)alloc((size_t)E * 4);
    float*    s_node    = (float*)alloc((size_t)N * 4);
    float*    w2l       = (float*)alloc(64 * 4);
    float*    c0        = (float*)alloc(4);
    _Float16* wt        = (_Float16*)alloc(64 * 128 * 2);
    uint2*    ebuf      = (uint2*)alloc((size_t)E * 8);
    unsigned* cnt       = (unsigned*)alloc(256 * 4);
    unsigned* segBase   = (unsigned*)alloc(256 * 4);
    unsigned* partial_s = (unsigned*)alloc((size_t)NPAIR * C * B * 4);
    unsigned* partial_d = (unsigned*)alloc((size_t)NPAIR * C * B * 4);

    float* out = (float*)d_out;
    const size_t ldsB = (size_t)B * 4;

    k_hist<<<dim3(NPAIR * C, 2), 256, ldsB, stream>>>(src, dst, partial_s, partial_d,
                                                      cnt, E, B, C, chunkE);
    k_w2l<<<1, 64, 0, stream>>>(W2, b2, Wl, bl, w2l, c0);
    k_wt<<<1, 256, 0, stream>>>(W1, wt);
    k_scancnt<<<1, 256, 0, stream>>>(cnt, segBase, nseg);
    k_bucket<<<C, 256, 0, stream>>>(src, dst, segBase, ebuf, E, B, C, chunkE);

    k_reduce_norm<<<(NPAIR * B + 255) / 256, 256, 0, stream>>>(partial_s, partial_d,
                                                               norm_s, norm_d,
                                                               deg_d, N, B, C);
    k_blocksum<<<NB, 256, 0, stream>>>(deg_d, partial, N);
    k_scanpartial<<<1, 512, 0, stream>>>(partial, blockoff, offsets, NB, N);
    k_offsets<<<NB, 256, 0, stream>>>(deg_d, blockoff, offsets, N);

    k_fill2<<<nseg, 256, ldsB, stream>>>(ebuf, segBase, cnt, offsets, partial_d,
                                         csr, N, B, C);

    k_gemm1<<<(N + 63) / 64, 256, 0, stream>>>(x, wt, norm_s, h1h, N);

    k_agg_rdot<<<(N + 3) / 4, 256, 0, stream>>>(offsets, csr, h1h, norm_s, norm_d,
                                                b1, w2l, s_node, N);
    k_out<<<NB, 256, 0, stream>>>(offsets, csr, s_node, norm_d, c0, out, N);
}

// Round 10
// 192.874 us; speedup vs baseline: 2.4062x; 2.4062x over previous
//
#include <hip/hip_runtime.h>
#include <hip/hip_fp16.h>

// GCN on MI355X — bucket-sort CSR build (fixed parallelism) + fp16 gather + MFMA.
//
// Algebra: layer2 collapses through the linear head:
//   out = segsum((relu(c1) . (W2@Wl) * ns)[src], dst)*nd + (b2@Wl + bl)
// so only a per-node SCALAR feeds the second aggregation.
//
// R9 change (fix of R8): k_bucket ran at 1.4% occupancy (grid was C=32 blocks).
// Bucket grid now CB=1024 chunks with its own count pass (k_cnt) and scan
// (k_scancnt2). fill2 reads the contiguous ebuf span covering its hist-chunk
// (RB = CB/C bucket segments). Hist reverted to R7 form.

#define WAVE 64
#define NRANGE 8
#define NPAIR 4
#define CB 1024

typedef _Float16 f16x8 __attribute__((ext_vector_type(8)));
typedef float f32x4 __attribute__((ext_vector_type(4)));

// ---- packed histogram: block (pr,c) covers ranges {2pr, 2pr+1}; y: src/dst ----
__global__ __launch_bounds__(256) void k_hist(const int* __restrict__ srcArr,
                                              const int* __restrict__ dstArr,
                                              unsigned* __restrict__ partial_s,
                                              unsigned* __restrict__ partial_d,
                                              int E, int B, int C, int chunkE) {
    extern __shared__ unsigned hist[];
    const int pr = blockIdx.x & (NPAIR - 1);
    const int c = blockIdx.x >> 2;
    const int lo = pr * 2 * B;
    const int* nodes = blockIdx.y ? dstArr : srcArr;
    unsigned* partial = blockIdx.y ? partial_d : partial_s;

    for (int b = threadIdx.x; b < B; b += 256) hist[b] = 0u;
    __syncthreads();

    const int beg = c * chunkE, end = min(beg + chunkE, E);
    const int n4 = (end - beg) >> 2;           // beg 4-aligned (chunkE %4==0)
    const int4* p = (const int4*)(nodes + beg);
    for (int j = threadIdx.x; j < n4; j += 256) {
        int4 v = p[j];
        int a;
        a = v.x - lo; if ((unsigned)a < (unsigned)(2 * B)) { int h = a >= B; atomicAdd(&hist[a - (h ? B : 0)], h ? 0x10000u : 1u); }
        a = v.y - lo; if ((unsigned)a < (unsigned)(2 * B)) { int h = a >= B; atomicAdd(&hist[a - (h ? B : 0)], h ? 0x10000u : 1u); }
        a = v.z - lo; if ((unsigned)a < (unsigned)(2 * B)) { int h = a >= B; atomicAdd(&hist[a - (h ? B : 0)], h ? 0x10000u : 1u); }
        a = v.w - lo; if ((unsigned)a < (unsigned)(2 * B)) { int h = a >= B; atomicAdd(&hist[a - (h ? B : 0)], h ? 0x10000u : 1u); }
    }
    for (int j = beg + (n4 << 2) + threadIdx.x; j < end; j += 256) {
        int a = nodes[j] - lo;
        if ((unsigned)a < (unsigned)(2 * B)) { int h = a >= B; atomicAdd(&hist[a - (h ? B : 0)], h ? 0x10000u : 1u); }
    }
    __syncthreads();
    unsigned* outp = partial + (size_t)(pr * C + c) * B;
    for (int b = threadIdx.x; b < B; b += 256) outp[b] = hist[b];
}

// ---- per bin-pair: sum packed partials -> norms/deg; packed exclusive prefix ----
__global__ __launch_bounds__(256) void k_reduce_norm(const unsigned* __restrict__ partial_s,
                                                     unsigned* __restrict__ partial_d,
                                                     float* __restrict__ norm_s,
                                                     float* __restrict__ norm_d,
                                                     unsigned* __restrict__ deg_d,
                                                     int N, int B, int C) {
    int t = blockIdx.x * 256 + threadIdx.x;   // [0, NPAIR*B)
    if (t >= NPAIR * B) return;
    int pr = t / B, b = t - pr * B;
    int n0 = pr * 2 * B + b, n1 = n0 + B;
    size_t base = (size_t)(pr * C) * B + b;
    unsigned ds = 0;
    for (int c = 0; c < C; ++c) ds += partial_s[base + (size_t)c * B];  // packed; halves can't carry
    unsigned run = 0;
    for (int c = 0; c < C; ++c) {
        size_t ix = base + (size_t)c * B;
        unsigned v = partial_d[ix];
        partial_d[ix] = run;                    // packed exclusive prefix
        run += v;
    }
    unsigned ds0 = ds & 0xffffu, ds1 = ds >> 16;
    unsigned dd0 = run & 0xffffu, dd1 = run >> 16;
    if (n0 < N) {
        deg_d[n0] = dd0;
        norm_s[n0] = ds0 ? rsqrtf((float)ds0) : 0.0f;
        norm_d[n0] = dd0 ? rsqrtf((float)dd0) : 0.0f;
    }
    if (n1 < N) {
        deg_d[n1] = dd1;
        norm_s[n1] = ds1 ? rsqrtf((float)ds1) : 0.0f;
        norm_d[n1] = dd1 ? rsqrtf((float)dd1) : 0.0f;
    }
}

// w2l[c] = sum_j W2[c][j]*Wl[j]; c0 = b2.Wl + bl
__global__ void k_w2l(const float* __restrict__ W2, const float* __restrict__ b2,
                      const float* __restrict__ Wl, const float* __restrict__ bl,
                      float* __restrict__ w2l, float* __restrict__ c0) {
    int c = threadIdx.x; // 64 threads
    float acc = 0.f;
#pragma unroll
    for (int j = 0; j < 32; ++j) acc += W2[c * 32 + j] * Wl[j];
    w2l[c] = acc;
    if (c == 0) {
        float s = 0.f;
#pragma unroll
        for (int j = 0; j < 32; ++j) s += b2[j] * Wl[j];
        *c0 = s + bl[0];
    }
}

// ---- W1 [128][64] fp32 -> wt [64][128] fp16 (transposed), once ----
__global__ __launch_bounds__(256) void k_wt(const float* __restrict__ W1,
                                            _Float16* __restrict__ wt) {
    int t = threadIdx.x;
    for (int i = 0; i < 32; ++i) {
        int e = i * 256 + t;       // 8192 elements
        int k = e >> 6, n = e & 63;
        wt[n * 128 + k] = (_Float16)W1[e];
    }
}

// ---- scan: deg_d -> exclusive offsets (N+1) ----
__global__ __launch_bounds__(256) void k_blocksum(const unsigned* __restrict__ deg,
                                                  unsigned* __restrict__ partial, int N) {
    __shared__ unsigned sw[4];
    int i = blockIdx.x * 256 + threadIdx.x;
    unsigned v = (i < N) ? deg[i] : 0u;
#pragma unroll
    for (int off = 32; off; off >>= 1) v += __shfl_xor((int)v, off);
    if ((threadIdx.x & 63) == 0) sw[threadIdx.x >> 6] = v;
    __syncthreads();
    if (threadIdx.x == 0) partial[blockIdx.x] = sw[0] + sw[1] + sw[2] + sw[3];
}

__global__ __launch_bounds__(512) void k_scanpartial(const unsigned* __restrict__ partial,
                                                     unsigned* __restrict__ blockoff,
                                                     unsigned* __restrict__ offsets,
                                                     int nb, int N) {
    __shared__ unsigned s[512];
    int t = threadIdx.x;
    unsigned v = (t < nb) ? partial[t] : 0u;
    s[t] = v;
    __syncthreads();
    for (int off = 1; off < 512; off <<= 1) {
        unsigned a = (t >= off) ? s[t - off] : 0u;
        __syncthreads();
        s[t] += a;
        __syncthreads();
    }
    if (t < nb) blockoff[t] = s[t] - v;       // exclusive
    if (t == nb - 1) offsets[N] = s[t];       // total = E
}

__global__ __launch_bounds__(256) void k_offsets(const unsigned* __restrict__ deg,
                                                 const unsigned* __restrict__ blockoff,
                                                 unsigned* __restrict__ offsets, int N) {
    __shared__ unsigned s[256];
    int t = threadIdx.x;
    int i = blockIdx.x * 256 + t;
    unsigned v = (i < N) ? deg[i] : 0u;
    s[t] = v;
    __syncthreads();
    for (int off = 1; off < 256; off <<= 1) {
        unsigned a = (t >= off) ? s[t - off] : 0u;
        __syncthreads();
        s[t] += a;
        __syncthreads();
    }
    if (i < N) offsets[i] = blockoff[blockIdx.x] + s[t] - v;
}

// ---- per-(range, bucket-chunk) counts: per-lane unrolled counters + reduce ----
__global__ __launch_bounds__(256) void k_cnt(const int* __restrict__ dst,
                                             unsigned* __restrict__ cnt,
                                             int E, int B, int chunkEb) {
    __shared__ unsigned lc[NRANGE];
    if (threadIdx.x < NRANGE) lc[threadIdx.x] = 0u;
    __syncthreads();
    const int c = blockIdx.x;
    const int beg = c * chunkEb, end = min(beg + chunkEb, E);
    unsigned pc[NRANGE] = {};
    for (int i = beg + (int)threadIdx.x; i < end; i += 256) {
        int r = dst[i] / B;
#pragma unroll
        for (int rr = 0; rr < NRANGE; ++rr) pc[rr] += (r == rr);
    }
#pragma unroll
    for (int rr = 0; rr < NRANGE; ++rr) {
        unsigned v = pc[rr];
#pragma unroll
        for (int off = 32; off; off >>= 1) v += __shfl_xor((int)v, off);
        if ((threadIdx.x & 63) == 0 && v) atomicAdd(&lc[rr], v);
    }
    __syncthreads();
    if (threadIdx.x < NRANGE) cnt[threadIdx.x * CB + c] = lc[threadIdx.x];
}

// ---- exclusive scan of cnt[NRANGE*CB] -> segBase[NRANGE*CB+1] (last = E) ----
__global__ __launch_bounds__(256) void k_scancnt2(const unsigned* __restrict__ cnt,
                                                  unsigned* __restrict__ segBase) {
    __shared__ unsigned s[256];
    const int t = threadIdx.x;
    const int PER = (NRANGE * CB) / 256;    // 32, compile-time
    unsigned loc[PER];
    unsigned sum = 0;
#pragma unroll
    for (int j = 0; j < PER; ++j) { loc[j] = sum; sum += cnt[t * PER + j]; }
    s[t] = sum;
    __syncthreads();
    for (int off = 1; off < 256; off <<= 1) {
        unsigned a = (t >= off) ? s[t - off] : 0u;
        __syncthreads();
        s[t] += a;
        __syncthreads();
    }
    unsigned base = s[t] - sum;             // exclusive block prefix
#pragma unroll
    for (int j = 0; j < PER; ++j) segBase[t * PER + j] = base + loc[j];
    if (t == 255) segBase[NRANGE * CB] = s[255];
}

// ---- bucketize: read edges ONCE (CB blocks); ballot-ranked append (src,dst)
//      into per-(range, bucket-chunk) segments of ebuf. No global atomics. ----
__global__ __launch_bounds__(256) void k_bucket(const int* __restrict__ src,
                                                const int* __restrict__ dst,
                                                const unsigned* __restrict__ segBase,
                                                uint2* __restrict__ ebuf,
                                                int E, int B, int chunkEb) {
    __shared__ unsigned lcnt[NRANGE];
    const int c = blockIdx.x;
    const int lane = threadIdx.x & 63;
    if (threadIdx.x < NRANGE) lcnt[threadIdx.x] = 0u;
    __syncthreads();

    unsigned sb[NRANGE];
#pragma unroll
    for (int r = 0; r < NRANGE; ++r) sb[r] = segBase[r * CB + c];

    const int beg = c * chunkEb, end = min(beg + chunkEb, E);
    for (int i = beg + (int)threadIdx.x; i < end; i += 256) {
        int d = dst[i];
        int s = src[i];
        int r = d / B;
#pragma unroll
        for (int rr = 0; rr < NRANGE; ++rr) {
            unsigned long long m = __ballot(r == rr);
            if (m) {
                int leader = __ffsll((long long)m) - 1;
                unsigned base = 0;
                if (lane == leader) base = atomicAdd(&lcnt[rr], (unsigned)__popcll(m));
                base = (unsigned)__shfl((int)base, leader);
                if (r == rr) {
                    unsigned before = (unsigned)__popcll(m & ((1ull << lane) - 1ull));
                    ebuf[sb[rr] + base + before] = make_uint2((unsigned)s, (unsigned)d);
                }
            }
        }
    }
}

// ---- fill2: block (r,ch) reads ONLY its contiguous ebuf span (RB segments);
//      LDS cursors hold ABSOLUTE csr positions; r=blockIdx&7 -> XCD-aligned ----
__global__ __launch_bounds__(256) void k_fill2(const uint2* __restrict__ ebuf,
                                               const unsigned* __restrict__ segBase,
                                               const unsigned* __restrict__ offsets,
                                               const unsigned* __restrict__ rel,
                                               unsigned* __restrict__ csr,
                                               int N, int B, int C, int RB) {
    extern __shared__ unsigned curs[];
    const int r = blockIdx.x & (NRANGE - 1);
    const int ch = blockIdx.x >> 3;
    const int lo = r * B;
    const int bins = min(B, N - lo);
    const int pr = r >> 1, hs = (r & 1) << 4;
    const unsigned* relp = rel + (size_t)(pr * C + ch) * B;
    for (int b = threadIdx.x; b < bins; b += 256)
        curs[b] = offsets[lo + b] + ((relp[b] >> hs) & 0xffffu);
    __syncthreads();

    const unsigned s0 = segBase[r * CB + ch * RB];
    const unsigned s1 = segBase[r * CB + ch * RB + RB];   // contiguous; wraps to next range/E
    for (unsigned i = s0 + threadIdx.x; i < s1; i += 256) {
        uint2 e = ebuf[i];
        int a = (int)e.y - lo;
        if ((unsigned)a < (unsigned)bins)
            csr[atomicAdd(&curs[a], 1u)] = e.x;
    }
}

// h1h = fp16( (x * ns[:,None]) @ W1 )  via MFMA 16x16x32_f16.
__global__ __launch_bounds__(256) void k_gemm1(const float* __restrict__ x,
                                               const _Float16* __restrict__ wt,
                                               const float* __restrict__ norm_s,
                                               __half* __restrict__ h1h, int N) {
    __shared__ __align__(16) _Float16 xs[64 * 128];
    const int tid = threadIdx.x, lane = tid & 63, wv = tid >> 6;
    const int r0 = blockIdx.x * 64;

    // B fragments: col = nt*16 + (lane&15), k = kt*32 + (lane>>4)*8 + b
    f16x8 bf[4][4];
#pragma unroll
    for (int kt = 0; kt < 4; ++kt)
#pragma unroll
        for (int nt = 0; nt < 4; ++nt)
            bf[kt][nt] = *(const f16x8*)&wt[(nt * 16 + (lane & 15)) * 128 +
                                            kt * 32 + (lane >> 4) * 8];

    // stage x tile -> fp16 LDS, swizzled (byte ^= (r&7)<<4)
#pragma unroll
    for (int it = 0; it < 8; ++it) {
        int e = it * 256 + tid;              // float4 index, 2048 total
        int r = e >> 5, c = e & 31;          // row, float4-within-row
        int row = r0 + r;
        float4 v = (row < N) ? ((const float4*)x)[(size_t)row * 32 + c]
                             : make_float4(0.f, 0.f, 0.f, 0.f);
        __half2 lo2 = __floats2half2_rn(v.x, v.y);
        __half2 hi2 = __floats2half2_rn(v.z, v.w);
        uint2 pk;
        pk.x = *(unsigned*)&lo2;
        pk.y = *(unsigned*)&hi2;
        int byte = r * 256 + c * 8;
        byte ^= (r & 7) << 4;
        *(uint2*)((char*)xs + byte) = pk;
    }
    __syncthreads();

    f32x4 acc[4] = {};
    const int rloc = wv * 16 + (lane & 15);   // A row within block tile
#pragma unroll
    for (int kt = 0; kt < 4; ++kt) {
        int byte = rloc * 256 + (kt * 32 + (lane >> 4) * 8) * 2;
        byte ^= (rloc & 7) << 4;
        f16x8 af = *(const f16x8*)((char*)xs + byte);
#pragma unroll
        for (int nt = 0; nt < 4; ++nt)
            acc[nt] = __builtin_amdgcn_mfma_f32_16x16x32_f16(af, bf[kt][nt], acc[nt], 0, 0, 0);
    }

    // D: col = nt*16 + (lane&15), row = wv*16 + (lane>>4)*4 + j
#pragma unroll
    for (int j = 0; j < 4; ++j) {
        int row = r0 + wv * 16 + (lane >> 4) * 4 + j;
        if (row < N) {
            float ns = norm_s[row];
#pragma unroll
            for (int nt = 0; nt < 4; ++nt)
                h1h[(size_t)row * 64 + nt * 16 + (lane & 15)] =
                    __float2half(acc[nt][j] * ns);
        }
    }
}

// One wave per node; coalesced csr load + shfl broadcast; 2 edges per step
// (lanes 0-31 / 32-63), __half2 per lane = 256B/instr; 8 gathers in flight.
__global__ __launch_bounds__(256) void k_agg_rdot(const unsigned* __restrict__ offsets,
                                                  const unsigned* __restrict__ csr,
                                                  const __half* __restrict__ h1h,
                                                  const float* __restrict__ norm_s,
                                                  const float* __restrict__ norm_d,
                                                  const float* __restrict__ b1,
                                                  const float* __restrict__ w2l,
                                                  float* __restrict__ s_node, int N) {
    const int lane = threadIdx.x & 63;
    const int slot = lane >> 5;    // which edge of the pair
    const int p = lane & 31;       // channel pair -> channels 2p, 2p+1
    const int v = (blockIdx.x * 256 + threadIdx.x) >> 6;
    if (v >= N) return;
    const unsigned beg = offsets[v], end = offsets[v + 1];

    float ax = 0.f, ay = 0.f;
    for (unsigned base = beg; base < end; base += WAVE) {
        const int n = (int)min((unsigned)WAVE, end - base);
        int sv = (lane < n) ? (int)csr[base + lane] : 0;
        int i = 0;
        for (; i + 16 <= n; i += 16) {  // 8 independent 256B gathers in flight
            int s0 = __shfl(sv, i + 0 + slot);
            int s1 = __shfl(sv, i + 2 + slot);
            int s2 = __shfl(sv, i + 4 + slot);
            int s3 = __shfl(sv, i + 6 + slot);
            int s4 = __shfl(sv, i + 8 + slot);
            int s5 = __shfl(sv, i + 10 + slot);
            int s6 = __shfl(sv, i + 12 + slot);
            int s7 = __shfl(sv, i + 14 + slot);
            unsigned u0 = *(const unsigned*)&h1h[(size_t)s0 * 64 + 2 * p];
            unsigned u1 = *(const unsigned*)&h1h[(size_t)s1 * 64 + 2 * p];
            unsigned u2 = *(const unsigned*)&h1h[(size_t)s2 * 64 + 2 * p];
            unsigned u3 = *(const unsigned*)&h1h[(size_t)s3 * 64 + 2 * p];
            unsigned u4 = *(const unsigned*)&h1h[(size_t)s4 * 64 + 2 * p];
            unsigned u5 = *(const unsigned*)&h1h[(size_t)s5 * 64 + 2 * p];
            unsigned u6 = *(const unsigned*)&h1h[(size_t)s6 * 64 + 2 * p];
            unsigned u7 = *(const unsigned*)&h1h[(size_t)s7 * 64 + 2 * p];
            float2 f0 = __half22float2(*(__half2*)&u0);
            float2 f1 = __half22float2(*(__half2*)&u1);
            float2 f2 = __half22float2(*(__half2*)&u2);
            float2 f3 = __half22float2(*(__half2*)&u3);
            float2 f4 = __half22float2(*(__half2*)&u4);
            float2 f5 = __half22float2(*(__half2*)&u5);
            float2 f6 = __half22float2(*(__half2*)&u6);
            float2 f7 = __half22float2(*(__half2*)&u7);
            ax += ((f0.x + f1.x) + (f2.x + f3.x)) + ((f4.x + f5.x) + (f6.x + f7.x));
            ay += ((f0.y + f1.y) + (f2.y + f3.y)) + ((f4.y + f5.y) + (f6.y + f7.y));
        }
        for (; i + 8 <= n; i += 8) {
            int s0 = __shfl(sv, i + 0 + slot);
            int s1 = __shfl(sv, i + 2 + slot);
            int s2 = __shfl(sv, i + 4 + slot);
            int s3 = __shfl(sv, i + 6 + slot);
            unsigned u0 = *(const unsigned*)&h1h[(size_t)s0 * 64 + 2 * p];
            unsigned u1 = *(const unsigned*)&h1h[(size_t)s1 * 64 + 2 * p];
            unsigned u2 = *(const unsigned*)&h1h[(size_t)s2 * 64 + 2 * p];
            unsigned u3 = *(const unsigned*)&h1h[(size_t)s3 * 64 + 2 * p];
            float2 f0 = __half22float2(*(__half2*)&u0);
            float2 f1 = __half22float2(*(__half2*)&u1);
            float2 f2 = __half22float2(*(__half2*)&u2);
            float2 f3 = __half22float2(*(__half2*)&u3);
            ax += (f0.x + f1.x) + (f2.x + f3.x);
            ay += (f0.y + f1.y) + (f2.y + f3.y);
        }
        for (; i < n; i += 2) {
            int e = i + slot;
            int s = __shfl(sv, min(e, n - 1));
            if (e < n) {
                unsigned u = *(const unsigned*)&h1h[(size_t)s * 64 + 2 * p];
                float2 f = __half22float2(*(__half2*)&u);
                ax += f.x; ay += f.y;
            }
        }
    }
    // merge the two edge-slots: lanes l and l^32 hold the same channel pair
    ax += __shfl_xor(ax, 32);
    ay += __shfl_xor(ay, 32);

    float nd = norm_d[v];
    float t = fmaxf(fmaf(ax, nd, b1[2 * p]), 0.f) * w2l[2 * p]
            + fmaxf(fmaf(ay, nd, b1[2 * p + 1]), 0.f) * w2l[2 * p + 1];
#pragma unroll
    for (int off = 16; off; off >>= 1) t += __shfl_xor(t, off);
    if (lane == 0) s_node[v] = t * norm_s[v];
}

// out[v] = nd[v] * sum_{in-edges} s_node[src] + c0
__global__ __launch_bounds__(256) void k_out(const unsigned* __restrict__ offsets,
                                             const unsigned* __restrict__ csr,
                                             const float* __restrict__ s_node,
                                             const float* __restrict__ norm_d,
                                             const float* __restrict__ c0,
                                             float* __restrict__ out, int N) {
    int v = blockIdx.x * 256 + threadIdx.x;
    if (v >= N) return;
    unsigned beg = offsets[v], end = offsets[v + 1];
    float sum = 0.f;
    unsigned j = beg;
    for (; j + 4 <= end; j += 4) {
        float a = s_node[csr[j + 0]], b = s_node[csr[j + 1]];
        float c = s_node[csr[j + 2]], d = s_node[csr[j + 3]];
        sum += a + b + c + d;
    }
    for (; j < end; ++j) sum += s_node[csr[j]];
    out[v] = fmaf(sum, norm_d[v], *c0);
}

extern "C" void kernel_launch(void* const* d_in, const int* in_sizes, int n_in,
                              void* d_out, int out_size, void* d_ws, size_t ws_size,
                              hipStream_t stream) {
    const float* x  = (const float*)d_in[0];
    const int*   ei = (const int*)d_in[1];
    const float* W1 = (const float*)d_in[2];
    const float* b1 = (const float*)d_in[3];
    const float* W2 = (const float*)d_in[4];
    const float* b2 = (const float*)d_in[5];
    const float* Wl = (const float*)d_in[6];
    const float* bl = (const float*)d_in[7];

    const int N = in_sizes[0] / 128;
    const int E = in_sizes[1] / 2;
    const int* src = ei;
    const int* dst = ei + E;
    const int NB = (N + 255) / 256;
    const int B = (N + NRANGE - 1) / NRANGE;       // bins per range (12500)

    // pick hist chunk count C so packed partials + ebuf fit the workspace
    size_t baseBytes = 0;
    {
        auto pad = [](size_t b) { return (b + 255) & ~(size_t)255; };
        baseBytes = pad((size_t)N * 4) * 3 + pad((size_t)(N + 1) * 4) +
                    pad((size_t)NB * 4) * 2 + pad((size_t)N * 64 * 2) +
                    pad((size_t)E * 4) + pad((size_t)N * 4) + pad(64 * 4) + pad(4) +
                    pad(64 * 128 * 2) + pad((size_t)E * 8) +
                    pad((size_t)(NRANGE * CB + 1) * 4) * 2;
    }
    int C = 32;
    while (C > 4 && baseBytes + 2ull * NPAIR * C * B * 4ull > ws_size) C >>= 1;
    const int chunkEb = (E + CB - 1) / CB;          // bucket chunk (~1563)
    const int RB = CB / C;                          // bucket chunks per hist chunk
    const int chunkE = chunkEb * RB;                // hist chunk; %4==0 (RB%4==0)

    char* w = (char*)d_ws;
    auto alloc = [&](size_t bytes) -> void* {
        void* r = (void*)w;
        w += (bytes + 255) & ~(size_t)255;
        return r;
    };
    float*    norm_s    = (float*)alloc((size_t)N * 4);
    float*    norm_d    = (float*)alloc((size_t)N * 4);
    unsigned* deg_d     = (unsigned*)alloc((size_t)N * 4);
    unsigned* offsets   = (unsigned*)alloc((size_t)(N + 1) * 4);
    unsigned* partial   = (unsigned*)alloc((size_t)NB * 4);
    unsigned* blockoff  = (unsigned*)alloc((size_t)NB * 4);
    __half*   h1h       = (__half*)alloc((size_t)N * 64 * 2);
    unsigned* csr       = (unsigned*)alloc((size_t)E * 4);
    float*    s_node    = (float*)alloc((size_t)N * 4);
    float*    w2l       = (float*)alloc(64 * 4);
    float*    c0        = (float*)alloc(4);
    _Float16* wt        = (_Float16*)alloc(64 * 128 * 2);
    uint2*    ebuf      = (uint2*)alloc((size_t)E * 8);
    unsigned* cnt       = (unsigned*)alloc((size_t)(NRANGE * CB + 1) * 4);
    unsigned* segBase   = (unsigned*)alloc((size_t)(NRANGE * CB + 1) * 4);
    unsigned* partial_s = (unsigned*)alloc((size_t)NPAIR * C * B * 4);
    unsigned* partial_d = (unsigned*)alloc((size_t)NPAIR * C * B * 4);

    float* out = (float*)d_out;
    const size_t ldsB = (size_t)B * 4;

    k_cnt<<<CB, 256, 0, stream>>>(dst, cnt, E, B, chunkEb);
    k_scancnt2<<<1, 256, 0, stream>>>(cnt, segBase);
    k_bucket<<<CB, 256, 0, stream>>>(src, dst, segBase, ebuf, E, B, chunkEb);

    k_hist<<<dim3(NPAIR * C, 2), 256, ldsB, stream>>>(src, dst, partial_s, partial_d,
                                                      E, B, C, chunkE);
    k_w2l<<<1, 64, 0, stream>>>(W2, b2, Wl, bl, w2l, c0);
    k_wt<<<1, 256, 0, stream>>>(W1, wt);

    k_reduce_norm<<<(NPAIR * B + 255) / 256, 256, 0, stream>>>(partial_s, partial_d,
                                                               norm_s, norm_d,
                                                               deg_d, N, B, C);
    k_blocksum<<<NB, 256, 0, stream>>>(deg_d, partial, N);
    k_scanpartial<<<1, 512, 0, stream>>>(partial, blockoff, offsets, NB, N);
    k_offsets<<<NB, 256, 0, stream>>>(deg_d, blockoff, offsets, N);

    k_fill2<<<NRANGE * C, 256, ldsB, stream>>>(ebuf, segBase, offsets, partial_d,
                                               csr, N, B, C, RB);

    k_gemm1<<<(N + 63) / 64, 256, 0, stream>>>(x, wt, norm_s, h1h, N);

    k_agg_rdot<<<(N + 3) / 4, 256, 0, stream>>>(offsets, csr, h1h, norm_s, norm_d,
                                                b1, w2l, s_node, N);
    k_out<<<NB, 256, 0, stream>>>(offsets, csr, s_node, norm_d, c0, out, N);
}